// Round 1
// baseline (2354.334 us; speedup 1.0000x reference)
//
#include <hip/hip_runtime.h>
#include <hip/hip_fp16.h>

#define T_LEN 192

typedef unsigned long long u64;
typedef _Float16 f16x8 __attribute__((ext_vector_type(8)));
typedef float f32x4 __attribute__((ext_vector_type(4)));

// ws float offsets
#define OFF_X1F   0          // X1F [192][64 tile][16 b][16 row] f32
#define OFF_XPRE  3145728    // [192][16][1024]
#define OFF_XB3   6291456    // x@Ws3 + Ws_b  [192][16][256]
#define OFF_HSB   7077888    // hsB [16][192][256]
#define OFF_P     7864320    // u64 [16][8][192]
#define OFF_R     7913472    // u64 [16][256]
#define OFF_H     7921664    // u64 [16][256]
#define OFF_HX    7929856    // (unused now; kept for layout stability)
#define EXCH_WORDS 81920

#define SMEM_TASK 156608
// lstm dynamic smem: W2L 131072 + hT 8704 + cst 16640
#define SMEM_LSTM 156416

__device__ __forceinline__ unsigned packh2(float a, float b){
  union { __half2 h; unsigned u; } v;
  v.h = __halves2half2(__float2half(a), __float2half(b));
  return v.u;
}
__device__ __forceinline__ float2 unp2(unsigned u){
  union { unsigned u32; __half2 h; } v; v.u32 = u;
  return __half22float2(v.h);
}
__device__ __forceinline__ float fdot2(unsigned a, unsigned b, float c){
#if __has_builtin(__builtin_amdgcn_fdot2)
  typedef _Float16 h2t __attribute__((ext_vector_type(2)));
  union { unsigned u; h2t h; } ua, ub;
  ua.u = a; ub.u = b;
  return __builtin_amdgcn_fdot2(ua.h, ub.h, c, false);
#else
  float2 x = unp2(a), y = unp2(b);
  return c + x.x*y.x + x.y*y.y;
#endif
}
__device__ __forceinline__ float tanh_f(float x){
  float cx = fminf(fmaxf(x, -15.f), 15.f);
  float e = __expf(2.f * cx);
  return (e - 1.f) / (e + 1.f);
}
__device__ __forceinline__ float sigm(float x){
  float cx = fminf(fmaxf(x, -30.f), 30.f);
  return 1.f / (1.f + __expf(-cx));
}

__device__ __forceinline__ u64 gld64(const u64* p){
  return __hip_atomic_load(p, __ATOMIC_RELAXED, __HIP_MEMORY_SCOPE_AGENT);
}
__device__ __forceinline__ void gst64(u64* p, u64 v){
  __hip_atomic_store(p, v, __ATOMIC_RELAXED, __HIP_MEMORY_SCOPE_AGENT);
}

__global__ __launch_bounds__(256) void initk(float* p, int n){
  int i = blockIdx.x * blockDim.x + threadIdx.x;
  int stride = gridDim.x * blockDim.x;
  for (; i < n; i += stride) p[i] = 0.f;
}

// fused x-projections: bx<32 -> X1F (MFMA-fragment layout), bx<64 -> xpre, else xb3
__global__ __launch_bounds__(256) void proj3(const float* __restrict__ x,
                                             const float* __restrict__ W_ih,
                                             const float* __restrict__ b_l,
                                             const float* __restrict__ Wc,
                                             const float* __restrict__ bc,
                                             const float* __restrict__ Ws_w,
                                             const float* __restrict__ Ws_b,
                                             float* __restrict__ ws){
  __shared__ float As[16 * 258];
  __shared__ float Wsh[256 * 34];
  const int bx = blockIdx.x, t = blockIdx.y, tid = threadIdx.x;
  const float* W; const float* bias; int ldw, woff, c0, mode; float* out;
  if (bx < 32)      { W = W_ih; bias = b_l;  ldw = 256; woff = 0;   c0 = bx * 32;        mode = 0; out = ws + OFF_X1F; }
  else if (bx < 64) { W = Wc;   bias = bc;   ldw = 768; woff = 0;   c0 = (bx - 32) * 32; mode = 1; out = ws + OFF_XPRE; }
  else              { W = Ws_w; bias = Ws_b; ldw = 768; woff = 512; c0 = (bx - 64) * 32; mode = 2; out = ws + OFF_XB3; }

  for (int i = 0; i < 16; ++i)
    As[i * 258 + tid] = x[(t * 16 + i) * 256 + tid];
  for (int i = 0; i < 32; ++i)
    Wsh[tid * 34 + i] = W[(c0 + i) * ldw + woff + tid];
  __syncthreads();

  const int r = tid >> 4;          // batch row within t
  const int c2 = (tid & 15) * 2;
  float acc0 = 0.f, acc1 = 0.f;
  for (int k = 0; k < 256; k += 2) {
    float2 a  = *(const float2*)&As[r * 258 + k];
    float2 w0 = *(const float2*)&Wsh[k * 34 + c2];
    float2 w1 = *(const float2*)&Wsh[(k + 1) * 34 + c2];
    acc0 = fmaf(a.x, w0.x, acc0); acc0 = fmaf(a.y, w1.x, acc0);
    acc1 = fmaf(a.x, w0.y, acc1); acc1 = fmaf(a.y, w1.y, acc1);
  }
  const int cg = c0 + c2;
  acc0 += bias[cg]; acc1 += bias[cg + 1];
  float2 res; res.x = acc0; res.y = acc1;
  if (mode == 0) {
    // X1F[t][tile = cg>>4][b = r][row = cg&15]; cg even so cg,cg+1 same tile
    *(float2*)&out[((t * 64 + (cg >> 4)) * 16 + r) * 16 + (cg & 15)] = res;
  } else if (mode == 1) {
    *(float2*)&out[(t * 16 + r) * 1024 + cg] = res;
  } else {
    *(float2*)&out[(t * 16 + r) * 256 + cg] = res;
  }
}

// Shared LSTM: SINGLE workgroup, 512 thr, 8 waves — zero cross-WG exchange.
// Wave w owns j-blocks {2w, 2w+1} (32 h-cols, all 4 gates = 128 W-rows).
// W_hh f16: K-slices kk=0..5 VGPR-resident (192 VGPR/lane), kk=6,7 in LDS (128 KB).
// h kept in LDS (hT); c-state in LDS (cstL); X1 added in epilogue (loads hidden
// under the MFMA chain). Two 8-wave barriers/step replace the global RTT.
__global__ __launch_bounds__(512, 2) void lstm_kernel(const float* __restrict__ X1F,
                                                      const float* __restrict__ W_hh,
                                                      float* __restrict__ hsB){
  extern __shared__ char smem[];
  unsigned* W2L = (unsigned*)smem;                 // 128 frags x 1024 B
  unsigned* hT  = (unsigned*)(smem + 131072);      // [16 b][136] u32 (f16 pairs)
  float*    cstL= (float*)(smem + 139776);         // [16 b][260] f32 (padded)

  const int tid = threadIdx.x;
  const int w = tid >> 6, lane = tid & 63;
  const int b16 = lane & 15, quad = lane >> 4;
  const int jb0 = w * 2;

  // ---- one-time: W fragments (A-frag: lane row m=b16, k=quad*8+j) ----
  f16x8 wf[2][4][6];
  #pragma unroll
  for (int jj = 0; jj < 2; ++jj)
    #pragma unroll
    for (int g = 0; g < 4; ++g)
      #pragma unroll
      for (int kk = 0; kk < 6; ++kk) {
        const float* wp = &W_hh[(g * 256 + (jb0 + jj) * 16 + b16) * 256 + kk * 32 + quad * 8];
        f16x8 v;
        #pragma unroll
        for (int j = 0; j < 8; ++j) v[j] = (_Float16)wp[j];
        wf[jj][g][kk] = v;
      }
  #pragma unroll
  for (int jj = 0; jj < 2; ++jj)
    #pragma unroll
    for (int g = 0; g < 4; ++g)
      #pragma unroll
      for (int kx = 0; kx < 2; ++kx) {
        const float* wp = &W_hh[(g * 256 + (jb0 + jj) * 16 + b16) * 256 + (6 + kx) * 32 + quad * 8];
        union { f16x8 h; uint4 u; } v;
        #pragma unroll
        for (int j = 0; j < 8; ++j) v.h[j] = (_Float16)wp[j];
        const int fi = (w * 8 + jj * 4 + g) * 2 + kx;
        *(uint4*)((char*)W2L + fi * 1024 + lane * 16) = v.u;
      }
  for (int i = tid; i < 16 * 136; i += 512) hT[i] = 0u;
  for (int i = tid; i < 16 * 260; i += 512) cstL[i] = 0.f;
  __syncthreads();

  for (int t = 0; t < T_LEN; ++t) {
    float hv[2][4];
    #pragma unroll
    for (int jj = 0; jj < 2; ++jj) {
      const int jb = jb0 + jj;
      // issue X1 loads early; consumed after the MFMA chain (latency hidden)
      float4 xi[4];
      #pragma unroll
      for (int g = 0; g < 4; ++g)
        xi[g] = *(const float4*)&X1F[((t * 64 + g * 16 + jb) * 16 + b16) * 16 + quad * 4];

      f32x4 acc[4];
      #pragma unroll
      for (int g = 0; g < 4; ++g) { f32x4 z = {0.f, 0.f, 0.f, 0.f}; acc[g] = z; }

      #pragma unroll
      for (int kk = 0; kk < 8; ++kk) {
        union { uint4 u; f16x8 h; } bv;
        bv.u = *(const uint4*)&hT[b16 * 136 + kk * 16 + quad * 4];
        if (kk < 6) {
          #pragma unroll
          for (int g = 0; g < 4; ++g)
            acc[g] = __builtin_amdgcn_mfma_f32_16x16x32_f16(wf[jj][g][kk], bv.h, acc[g], 0, 0, 0);
        } else {
          #pragma unroll
          for (int g = 0; g < 4; ++g) {
            union { uint4 u; f16x8 h; } wl;
            const int fi = (w * 8 + jj * 4 + g) * 2 + (kk - 6);
            wl.u = *(const uint4*)((const char*)W2L + fi * 1024 + lane * 16);
            acc[g] = __builtin_amdgcn_mfma_f32_16x16x32_f16(wl.h, bv.h, acc[g], 0, 0, 0);
          }
        }
      }

      const int j0 = jb * 16 + quad * 4;
      float4 cv = *(const float4*)&cstL[b16 * 260 + j0];
      float cw[4];
      #pragma unroll
      for (int r = 0; r < 4; ++r) {
        float pi = acc[0][r] + ((const float*)&xi[0])[r];
        float pf = acc[1][r] + ((const float*)&xi[1])[r];
        float pg = acc[2][r] + ((const float*)&xi[2])[r];
        float po = acc[3][r] + ((const float*)&xi[3])[r];
        float cold = ((const float*)&cv)[r];
        float cn = fmaf(sigm(pf), cold, sigm(pi) * tanh_f(pg));
        hv[jj][r] = sigm(po) * tanh_f(cn);
        cw[r] = cn;
      }
      *(float4*)&cstL[b16 * 260 + j0] = make_float4(cw[0], cw[1], cw[2], cw[3]);
    }
    __syncthreads();   // all hT(t-1) reads complete
    #pragma unroll
    for (int jj = 0; jj < 2; ++jj) {
      const int j0 = (jb0 + jj) * 16 + quad * 4;
      hT[b16 * 136 + (j0 >> 1)]     = packh2(hv[jj][0], hv[jj][1]);
      hT[b16 * 136 + (j0 >> 1) + 1] = packh2(hv[jj][2], hv[jj][3]);
      *(float4*)&hsB[(b16 * 192 + t) * 256 + j0] =
          make_float4(hv[jj][0], hv[jj][1], hv[jj][2], hv[jj][3]);
    }
    __syncthreads();   // hT(t) ready
  }
}

// Task loop: 128 WGs x 1024 thr; b = bid&15, s = bid>>4 owns c in [32s,32s+32).
// 3 seq-embedded exchanges/step (p scores, R final-normalized, h), all 1-RTT polls.
__global__ __launch_bounds__(1024) void task_kernel(
    const float* __restrict__ xb3, const float* __restrict__ xpre,
    const float* __restrict__ hsB, const float* __restrict__ Us_w,
    const float* __restrict__ Us_b, const float* __restrict__ Wc,
    const float* __restrict__ Ws_w,
    u64* __restrict__ Pbuf, u64* __restrict__ Rbuf, u64* __restrict__ Hbuf,
    float* __restrict__ out){
  extern __shared__ char smem[];
  // prologue views
  unsigned* hsL  = (unsigned*)smem;               // [192][129] u32 (f16x2)
  unsigned* Ws1L = (unsigned*)(smem + 99072);     // [32][129]
  float*    baseS= (float*)(smem + 115584);       // [192][33]
  // main views
  unsigned* WcH  = (unsigned*)smem;               // 32768 u32
  unsigned* Ws2L = (unsigned*)(smem + 131072);    // [32][130]
  float* scr     = (float*)(smem + 147712);       // [32][33] union
  float* prel    = (float*)(smem + 147712);       // [128][8] (same region, disjoint phase)
  float* eel     = (float*)(smem + 151936);       // 192
  float* rl      = (float*)(smem + 152704);       // 256
  float* hl      = (float*)(smem + 153728);       // 256
  unsigned* h2l  = (unsigned*)(smem + 154752);    // 128
  unsigned* actH = (unsigned*)(smem + 155264);    // 256: [R pairs | h pairs]
  float* hterml  = (float*)(smem + 156288);       // 32
  float* usl     = (float*)(smem + 156416);       // 32
  float* msc     = (float*)(smem + 156544);

  const int tid = threadIdx.x;
  const int bb = blockIdx.x & 15;
  const int s  = blockIdx.x >> 4;

  // ---- prologue P1: stage hs (f16) + Ws1 slice ----
  for (int idx = tid; idx < 24576; idx += 1024) {
    int tp = idx >> 7, k2 = idx & 127;
    const float* hp = &hsB[(bb * 192 + tp) * 256 + 2 * k2];
    hsL[tp * 129 + k2] = packh2(hp[0], hp[1]);
  }
  for (int idx = tid; idx < 4096; idx += 1024) {
    int c = idx >> 7, k2 = idx & 127;
    const float* wp = &Ws_w[(32 * s + c) * 768 + 2 * k2];
    Ws1L[c * 129 + k2] = packh2(wp[0], wp[1]);
  }
  __syncthreads();
  // ---- P2: base_s = xb3 + hs @ Ws1^T for [192 tp][own 32 c] ----
  {
    int c = tid & 31, g = tid >> 5;
    float a6[6];
    #pragma unroll
    for (int j = 0; j < 6; ++j)
      a6[j] = xb3[((g * 6 + j) * 16 + bb) * 256 + 32 * s + c];
    for (int k2 = 0; k2 < 128; ++k2) {
      unsigned wv = Ws1L[c * 129 + k2];
      #pragma unroll
      for (int j = 0; j < 6; ++j)
        a6[j] = fdot2(wv, hsL[(g * 6 + j) * 129 + k2], a6[j]);
    }
    #pragma unroll
    for (int j = 0; j < 6; ++j)
      baseS[(g * 6 + j) * 33 + c] = a6[j];
  }
  __syncthreads();
  // ---- P3: persistent registers: base (f16 pairs), hs for R ----
  unsigned bs4[4] = {0u, 0u, 0u, 0u};
  if (tid < 768) {
    int tp = tid >> 2, q = tid & 3;
    #pragma unroll
    for (int j2 = 0; j2 < 4; ++j2)
      bs4[j2] = packh2(baseS[tp * 33 + q * 8 + 2 * j2],
                       baseS[tp * 33 + q * 8 + 2 * j2 + 1]);
  }
  float hsr[6];
  {
    int c = tid & 31, g = tid >> 5;
    #pragma unroll
    for (int j = 0; j < 6; ++j)
      hsr[j] = hsB[(bb * 192 + g * 6 + j) * 256 + 32 * s + c];
  }
  __syncthreads();
  // ---- P4: main weight fills (overwrite prologue regions) ----
  for (int idx = tid; idx < 32768; idx += 1024) {
    int j = idx & 3, l = (idx >> 2) & 127, k2q = idx >> 9;
    int k2 = k2q * 4 + j;
    int row = (l >> 5) * 256 + 32 * s + (l & 31);
    const float* wp = &Wc[row * 768 + 256 + 2 * k2];
    WcH[idx] = packh2(wp[0], wp[1]);
  }
  for (int idx = tid; idx < 4096; idx += 1024) {
    int c = idx >> 7, k2 = idx & 127;
    const float* wp = &Ws_w[(32 * s + c) * 768 + 256 + 2 * k2];
    Ws2L[c * 130 + k2] = packh2(wp[0], wp[1]);
  }
  if (tid < 32) usl[tid] = Us_w[32 * s + tid];
  const float usb = Us_b[0];
  __syncthreads();

  u64* Pb = Pbuf + (bb * 8) * 192;
  u64* Rb = Rbuf + bb * 256;
  u64* Hb = Hbuf + bb * 256;
  const uint4* wp4 = (const uint4*)WcH;
  const uint4* av4 = (const uint4*)actH;
  float creg = 0.f;       // c-state (tid<32)

  for (int t = 0; t < T_LEN; ++t) {
    const unsigned seq = (unsigned)(t + 1);
    float xp0 = 0.f, xp1 = 0.f, xp2 = 0.f, xp3 = 0.f;
    if (tid < 32) {
      const float* xq = &xpre[(t * 16 + bb) * 1024 + 32 * s + tid];
      xp0 = xq[0]; xp1 = xq[256]; xp2 = xq[512]; xp3 = xq[768];
    }
    // S1: h(t-1) poll (single u64 per thread)
    if (tid < 256) {
      float hvv = 0.f;
      if (t > 0) {
        u64 v;
        do { v = gld64(&Hb[tid]); } while ((unsigned)v != (unsigned)t);
        hvv = __uint_as_float((unsigned)(v >> 32));
      }
      hl[tid] = hvv;
    }
    __syncthreads();                 // B1
    if (tid < 128) {
      unsigned u = packh2(hl[2 * tid], hl[2 * tid + 1]);
      h2l[tid] = u; actH[128 + tid] = u;
    }
    __syncthreads();                 // B2
    // S3: hterm_s = Ws2[c-slice,:] @ h  (local, no exchange)
    {
      int c = tid & 31, seg = tid >> 5;
      float a = 0.f;
      #pragma unroll
      for (int i = 0; i < 4; ++i)
        a = fdot2(Ws2L[c * 130 + seg * 4 + i], h2l[seg * 4 + i], a);
      scr[c * 33 + seg] = a;
    }
    __syncthreads();                 // B3
    if (tid < 32) {
      float a = 0.f;
      #pragma unroll 8
      for (int i = 0; i < 32; ++i) a += scr[tid * 33 + i];
      hterml[tid] = a;
    }
    __syncthreads();                 // B4
    // S5: score partials over own 32 c for all 192 tp; publish p_s
    if (tid < 768) {
      int tp = tid >> 2, q = tid & 3;
      float p = 0.f;
      #pragma unroll
      for (int m = 0; m < 4; ++m) {
        float2 bv = unp2(bs4[m]);
        int c0 = q * 8 + 2 * m;
        p += usl[c0]     * tanh_f(bv.x + hterml[c0]);
        p += usl[c0 + 1] * tanh_f(bv.y + hterml[c0 + 1]);
      }
      p += __shfl_xor(p, 1);
      p += __shfl_xor(p, 2);
      if ((tid & 3) == 0)
        gst64(&Pb[s * 192 + tp], ((u64)__float_as_uint(p) << 32) | seq);
    }
    // S6: p poll + exp (bounded scores, no max-sub)
    if (tid < 192) {
      u64 v[8];
      for (;;) {
        bool ok = true;
        #pragma unroll
        for (int sp = 0; sp < 8; ++sp) {
          v[sp] = gld64(&Pb[sp * 192 + tid]);
          ok &= ((unsigned)v[sp] == seq);
        }
        if (ok) break;
      }
      float sum = 0.f;
      #pragma unroll
      for (int sp = 0; sp < 8; ++sp) sum += __uint_as_float((unsigned)(v[sp] >> 32));
      eel[tid] = __expf(sum + usb);
    }
    __syncthreads();                 // B5
    // S7: L-reduce (wave0) + R partial (all, hs in regs)
    if (tid < 64) {
      float a = eel[tid] + eel[tid + 64] + eel[tid + 128];
      #pragma unroll
      for (int off = 32; off >= 1; off >>= 1) a += __shfl_xor(a, off);
      if (tid == 0) msc[0] = 1.f / a;
    }
    {
      int c = tid & 31, g = tid >> 5;
      float a = 0.f;
      #pragma unroll
      for (int j = 0; j < 6; ++j) a = fmaf(eel[g * 6 + j], hsr[j], a);
      scr[g * 33 + c] = a;
    }
    __syncthreads();                 // B6
    if (tid < 32) {
      float a = 0.f;
      #pragma unroll 8
      for (int g = 0; g < 32; ++g) a += scr[g * 33 + tid];
      a *= msc[0];                   // final normalized R slice
      gst64(&Rb[32 * s + tid], ((u64)__float_as_uint(a) << 32) | seq);
    }
    // S9: R poll (1 u64/thread)
    if (tid < 256) {
      u64 v;
      do { v = gld64(&Rb[tid]); } while ((unsigned)v != seq);
      rl[tid] = __uint_as_float((unsigned)(v >> 32));
    }
    __syncthreads();                 // B7
    if (tid < 128) actH[tid] = packh2(rl[2 * tid], rl[2 * tid + 1]);
    __syncthreads();                 // B8
    // S11: gates GEMV (K=512 f16): l = tid&127, K-eighth = tid>>7
    {
      int l = tid & 127, kq = tid >> 7;
      float a = 0.f;
      #pragma unroll
      for (int i = 0; i < 8; ++i) {
        uint4 w4 = wp4[(kq * 8 + i) * 128 + l];
        uint4 a4 = av4[kq * 8 + i];
        a = fdot2(w4.x, a4.x, a); a = fdot2(w4.y, a4.y, a);
        a = fdot2(w4.z, a4.z, a); a = fdot2(w4.w, a4.w, a);
      }
      prel[l * 8 + kq] = a;
    }
    __syncthreads();                 // B9
    if (tid < 32) {
      float pr[4];
      #pragma unroll
      for (int g = 0; g < 4; ++g) {
        const float4* pp = (const float4*)&prel[(g * 32 + tid) * 8];
        float4 p0 = pp[0], p1 = pp[1];
        pr[g] = p0.x + p0.y + p0.z + p0.w + p1.x + p1.y + p1.z + p1.w;
      }
      pr[0] += xp0; pr[1] += xp1; pr[2] += xp2; pr[3] += xp3;
      float cn = fmaf(sigm(pr[1]), creg, sigm(pr[0]) * tanh_f(pr[2]));
      float hh = sigm(pr[3]) * tanh_f(cn);
      creg = cn;
      out[(bb * 192 + t) * 256 + 32 * s + tid] = hh;
      gst64(&Hb[32 * s + tid], ((u64)__float_as_uint(hh) << 32) | seq);
    }
  }
}

extern "C" void kernel_launch(void* const* d_in, const int* in_sizes, int n_in,
                              void* d_out, int out_size, void* d_ws, size_t ws_size,
                              hipStream_t stream) {
  (void)in_sizes; (void)n_in; (void)out_size; (void)ws_size;
  const float* x    = (const float*)d_in[0];
  const float* W_ih = (const float*)d_in[1];
  const float* W_hh = (const float*)d_in[2];
  const float* b_l  = (const float*)d_in[3];
  const float* Ws_w = (const float*)d_in[4];
  const float* Ws_b = (const float*)d_in[5];
  const float* Us_w = (const float*)d_in[6];
  const float* Us_b = (const float*)d_in[7];
  const float* Wc   = (const float*)d_in[8];
  const float* bc   = (const float*)d_in[9];
  float* out = (float*)d_out;
  float* ws = (float*)d_ws;

  hipFuncSetAttribute((const void*)task_kernel,
                      hipFuncAttributeMaxDynamicSharedMemorySize, 160 * 1024);
  hipFuncSetAttribute((const void*)lstm_kernel,
                      hipFuncAttributeMaxDynamicSharedMemorySize, 160 * 1024);

  // zero exchange region (P, R, H — seq tags restart at 1 each launch)
  initk<<<64, 256, 0, stream>>>(ws + OFF_P, EXCH_WORDS);

  // fused x-projections: X1F, xpre, xb3
  proj3<<<dim3(72, 192), 256, 0, stream>>>(x, W_ih, b_l, Wc, bc, Ws_w, Ws_b, ws);

  // shared LSTM: single persistent WG, W_hh split VGPR(6/8 K)+LDS(2/8 K), no exchange
  lstm_kernel<<<1, 512, SMEM_LSTM, stream>>>(ws + OFF_X1F, W_hh, ws + OFF_HSB);

  // task loop
  task_kernel<<<128, 1024, SMEM_TASK, stream>>>(
      ws + OFF_XB3, ws + OFF_XPRE, ws + OFF_HSB, Us_w, Us_b, Wc, Ws_w,
      (u64*)(ws + OFF_P), (u64*)(ws + OFF_R), (u64*)(ws + OFF_H), out);
}

// Round 2
// 1949.606 us; speedup vs baseline: 1.2076x; 1.2076x over previous
//
#include <hip/hip_runtime.h>
#include <hip/hip_fp16.h>

#define T_LEN 192

typedef unsigned long long u64;
typedef _Float16 f16x8 __attribute__((ext_vector_type(8)));
typedef float f32x4 __attribute__((ext_vector_type(4)));

// ws float offsets
#define OFF_X1F   0          // X1F [192][64 tile][16 b][16 row] f32
#define OFF_XPRE  3145728    // [192][16][1024]
#define OFF_XB3   6291456    // x@Ws3 + Ws_b  [192][16][256]
#define OFF_HSB   7077888    // hsB [16][192][256]
#define OFF_P     7864320    // u64 [16][8][192]
#define OFF_R     7913472    // u64 [16][256]
#define OFF_H     7921664    // u64 [16][256]
#define OFF_HX    7929856    // u64 [2][256][16]
#define OFF_TICKET 7946240   // u32 [9]: cnt[8] + chosen
#define EXCH_WORDS 81936

#define SMEM_TASK 156608

__device__ __forceinline__ unsigned packh2(float a, float b){
  union { __half2 h; unsigned u; } v;
  v.h = __halves2half2(__float2half(a), __float2half(b));
  return v.u;
}
__device__ __forceinline__ float2 unp2(unsigned u){
  union { unsigned u32; __half2 h; } v; v.u32 = u;
  return __half22float2(v.h);
}
__device__ __forceinline__ float fdot2(unsigned a, unsigned b, float c){
#if __has_builtin(__builtin_amdgcn_fdot2)
  typedef _Float16 h2t __attribute__((ext_vector_type(2)));
  union { unsigned u; h2t h; } ua, ub;
  ua.u = a; ub.u = b;
  return __builtin_amdgcn_fdot2(ua.h, ub.h, c, false);
#else
  float2 x = unp2(a), y = unp2(b);
  return c + x.x*y.x + x.y*y.y;
#endif
}
__device__ __forceinline__ float tanh_f(float x){
  float cx = fminf(fmaxf(x, -15.f), 15.f);
  float e = __expf(2.f * cx);
  return (e - 1.f) / (e + 1.f);
}
__device__ __forceinline__ float sigm(float x){
  float cx = fminf(fmaxf(x, -30.f), 30.f);
  return 1.f / (1.f + __expf(-cx));
}

__device__ __forceinline__ u64 gld64(const u64* p){
  return __hip_atomic_load(p, __ATOMIC_RELAXED, __HIP_MEMORY_SCOPE_AGENT);
}
__device__ __forceinline__ void gst64(u64* p, u64 v){
  __hip_atomic_store(p, v, __ATOMIC_RELAXED, __HIP_MEMORY_SCOPE_AGENT);
}

__global__ __launch_bounds__(256) void initk(float* p, int n){
  int i = blockIdx.x * blockDim.x + threadIdx.x;
  int stride = gridDim.x * blockDim.x;
  for (; i < n; i += stride) p[i] = 0.f;
}

// fused x-projections: bx<32 -> X1F (MFMA-fragment layout), bx<64 -> xpre, else xb3
__global__ __launch_bounds__(256) void proj3(const float* __restrict__ x,
                                             const float* __restrict__ W_ih,
                                             const float* __restrict__ b_l,
                                             const float* __restrict__ Wc,
                                             const float* __restrict__ bc,
                                             const float* __restrict__ Ws_w,
                                             const float* __restrict__ Ws_b,
                                             float* __restrict__ ws){
  __shared__ float As[16 * 258];
  __shared__ float Wsh[256 * 34];
  const int bx = blockIdx.x, t = blockIdx.y, tid = threadIdx.x;
  const float* W; const float* bias; int ldw, woff, c0, mode; float* out;
  if (bx < 32)      { W = W_ih; bias = b_l;  ldw = 256; woff = 0;   c0 = bx * 32;        mode = 0; out = ws + OFF_X1F; }
  else if (bx < 64) { W = Wc;   bias = bc;   ldw = 768; woff = 0;   c0 = (bx - 32) * 32; mode = 1; out = ws + OFF_XPRE; }
  else              { W = Ws_w; bias = Ws_b; ldw = 768; woff = 512; c0 = (bx - 64) * 32; mode = 2; out = ws + OFF_XB3; }

  for (int i = 0; i < 16; ++i)
    As[i * 258 + tid] = x[(t * 16 + i) * 256 + tid];
  for (int i = 0; i < 32; ++i)
    Wsh[tid * 34 + i] = W[(c0 + i) * ldw + woff + tid];
  __syncthreads();

  const int r = tid >> 4;          // batch row within t
  const int c2 = (tid & 15) * 2;
  float acc0 = 0.f, acc1 = 0.f;
  for (int k = 0; k < 256; k += 2) {
    float2 a  = *(const float2*)&As[r * 258 + k];
    float2 w0 = *(const float2*)&Wsh[k * 34 + c2];
    float2 w1 = *(const float2*)&Wsh[(k + 1) * 34 + c2];
    acc0 = fmaf(a.x, w0.x, acc0); acc0 = fmaf(a.y, w1.x, acc0);
    acc1 = fmaf(a.x, w0.y, acc1); acc1 = fmaf(a.y, w1.y, acc1);
  }
  const int cg = c0 + c2;
  acc0 += bias[cg]; acc1 += bias[cg + 1];
  float2 res; res.x = acc0; res.y = acc1;
  if (mode == 0) {
    // X1F[t][tile = cg>>4][b = r][row = cg&15]; cg even so cg,cg+1 same tile
    *(float2*)&out[((t * 64 + (cg >> 4)) * 16 + r) * 16 + (cg & 15)] = res;
  } else if (mode == 1) {
    *(float2*)&out[(t * 16 + r) * 1024 + cg] = res;
  } else {
    *(float2*)&out[(t * 16 + r) * 256 + cg] = res;
  }
}

// Shared LSTM: 2 worker WGs x 512 thr, CO-LOCATED ON ONE XCD via ticket election.
// W_hh resident in VGPRs, MFMA 16x16x32_f16. Worker wg owns h-cols
// [wg*128, wg*128+128). Wave = j-block of 16 cols, all 4 gates.
// Cross-WG h exchange through the shared (same-XCD) L2 -> ~3x lower RTT than
// the cross-XCD default placement of a 2-block grid.
__global__ __launch_bounds__(512) void lstm_kernel(const float* __restrict__ X1F,
                                                   const float* __restrict__ W_hh,
                                                   float* __restrict__ hsB,
                                                   u64* __restrict__ hx,
                                                   unsigned* __restrict__ ticket){
  __shared__ unsigned hT[16 * 136];   // [b][k2], row stride 136 u32 (16B-aligned)
  __shared__ int role_s;
  const int tid = threadIdx.x;

  // ---- XCD co-location ticket: first XCD to register 2 blocks wins ----
  if (tid == 0) {
    // s_getreg hwreg(HW_REG_XCC_ID=20, offset=0, size=32) -> imm 20 | 31<<11
    int xcc = (int)__builtin_amdgcn_s_getreg(20 | (31 << 11)) & 7;
    unsigned slot = __hip_atomic_fetch_add(&ticket[xcc], 1u,
                        __ATOMIC_RELAXED, __HIP_MEMORY_SCOPE_AGENT);
    int role = -1;
    if (slot < 2u) {
      if (slot == 1u) {
        unsigned expv = 0u;
        __hip_atomic_compare_exchange_strong(&ticket[8], &expv, (unsigned)(xcc + 1),
            __ATOMIC_RELAXED, __ATOMIC_RELAXED, __HIP_MEMORY_SCOPE_AGENT);
      }
      unsigned ch;
      do {
        ch = __hip_atomic_load(&ticket[8], __ATOMIC_RELAXED, __HIP_MEMORY_SCOPE_AGENT);
      } while (ch == 0u);   // guaranteed: 16 blocks on 8 XCDs -> some XCD gets 2
      if (ch == (unsigned)(xcc + 1)) role = (int)slot;
    }
    role_s = role;
  }
  __syncthreads();
  const int wg = role_s;
  if (wg < 0) return;                 // non-elected blocks exit

  const int wave = tid >> 6, lane = tid & 63;
  const int b16 = lane & 15, quad = lane >> 4;
  const int jb = wg * 8 + wave;       // j-block 0..15
  const int peer0 = (1 - wg) * 128;

  // W fragments -> VGPRs (once)
  f16x8 wf[4][8];
  #pragma unroll
  for (int g = 0; g < 4; ++g) {
    #pragma unroll
    for (int kk = 0; kk < 8; ++kk) {
      int row = g * 256 + jb * 16 + b16;
      const float* wp = &W_hh[row * 256 + kk * 32 + quad * 8];
      f16x8 v;
      #pragma unroll
      for (int j = 0; j < 8; ++j) v[j] = (_Float16)wp[j];
      wf[g][kk] = v;
    }
  }
  for (int i = tid; i < 16 * 136; i += 512) hT[i] = 0u;
  float cst[4] = {0.f, 0.f, 0.f, 0.f};
  __syncthreads();

  for (int t = 0; t < T_LEN; ++t) {
    // prefetch X1 (C init) — independent of h
    float4 xi[4];
    #pragma unroll
    for (int g = 0; g < 4; ++g)
      xi[g] = *(const float4*)&X1F[((t * 64 + g * 16 + jb) * 16 + b16) * 16 + quad * 4];

    if (t > 0) {
      const u64* src = &hx[((u64)((t - 1) & 1) * 256) * 16];
      #pragma unroll
      for (int cc = 0; cc < 2; ++cc) {
        int idx = tid * 2 + cc;         // 0..1023: peer cells
        int jp = idx >> 4, bbq = idx & 15;
        int j0 = peer0 + jp * 2;
        u64 v0, v1;
        for (;;) {
          v0 = gld64(&src[(j0) * 16 + bbq]);
          v1 = gld64(&src[(j0 + 1) * 16 + bbq]);
          if ((unsigned)v0 == (unsigned)t && (unsigned)v1 == (unsigned)t) break;
        }
        hT[bbq * 136 + (j0 >> 1)] =
            packh2(__uint_as_float((unsigned)(v0 >> 32)),
                   __uint_as_float((unsigned)(v1 >> 32)));
      }
    }
    __syncthreads();     // hT(t-1) complete (own half from prev epilogue)

    f32x4 acc[4];
    #pragma unroll
    for (int g = 0; g < 4; ++g) {
      f32x4 a; a[0]=xi[g].x; a[1]=xi[g].y; a[2]=xi[g].z; a[3]=xi[g].w;
      acc[g] = a;
    }
    #pragma unroll
    for (int kk = 0; kk < 8; ++kk) {
      union { uint4 u; f16x8 h; } bv;
      bv.u = *(const uint4*)&hT[b16 * 136 + kk * 16 + quad * 4];
      #pragma unroll
      for (int g = 0; g < 4; ++g)
        acc[g] = __builtin_amdgcn_mfma_f32_16x16x32_f16(wf[g][kk], bv.h, acc[g], 0, 0, 0);
    }
    __syncthreads();     // all hT reads done before overwrite

    float hv[4];
    #pragma unroll
    for (int r = 0; r < 4; ++r) {
      float pi = acc[0][r], pf = acc[1][r], pg = acc[2][r], po = acc[3][r];
      float cn = fmaf(sigm(pf), cst[r], sigm(pi) * tanh_f(pg));
      hv[r] = sigm(po) * tanh_f(cn);
      cst[r] = cn;
    }
    int j0 = jb * 16 + quad * 4;
    *(float4*)&hsB[(b16 * 192 + t) * 256 + j0] = make_float4(hv[0], hv[1], hv[2], hv[3]);
    hT[b16 * 136 + (j0 >> 1)]     = packh2(hv[0], hv[1]);
    hT[b16 * 136 + (j0 >> 1) + 1] = packh2(hv[2], hv[3]);
    u64* dst = &hx[((u64)(t & 1) * 256) * 16];
    #pragma unroll
    for (int r = 0; r < 4; ++r)
      gst64(&dst[(j0 + r) * 16 + b16],
            ((u64)__float_as_uint(hv[r]) << 32) | (unsigned)(t + 1));
    // next-iter post-poll barrier orders own hT writes vs next reads
  }
}

// Task loop: 128 WGs x 1024 thr; b = bid&15, s = bid>>4 owns c in [32s,32s+32).
// 3 seq-embedded exchanges/step (p scores, R final-normalized, h), all 1-RTT polls.
__global__ __launch_bounds__(1024) void task_kernel(
    const float* __restrict__ xb3, const float* __restrict__ xpre,
    const float* __restrict__ hsB, const float* __restrict__ Us_w,
    const float* __restrict__ Us_b, const float* __restrict__ Wc,
    const float* __restrict__ Ws_w,
    u64* __restrict__ Pbuf, u64* __restrict__ Rbuf, u64* __restrict__ Hbuf,
    float* __restrict__ out){
  extern __shared__ char smem[];
  // prologue views
  unsigned* hsL  = (unsigned*)smem;               // [192][129] u32 (f16x2)
  unsigned* Ws1L = (unsigned*)(smem + 99072);     // [32][129]
  float*    baseS= (float*)(smem + 115584);       // [192][33]
  // main views
  unsigned* WcH  = (unsigned*)smem;               // 32768 u32
  unsigned* Ws2L = (unsigned*)(smem + 131072);    // [32][130]
  float* scr     = (float*)(smem + 147712);       // [32][33] union
  float* prel    = (float*)(smem + 147712);       // [128][8] (same region, disjoint phase)
  float* eel     = (float*)(smem + 151936);       // 192
  float* rl      = (float*)(smem + 152704);       // 256
  float* hl      = (float*)(smem + 153728);       // 256
  unsigned* h2l  = (unsigned*)(smem + 154752);    // 128
  unsigned* actH = (unsigned*)(smem + 155264);    // 256: [R pairs | h pairs]
  float* hterml  = (float*)(smem + 156288);       // 32
  float* usl     = (float*)(smem + 156416);       // 32
  float* msc     = (float*)(smem + 156544);

  const int tid = threadIdx.x;
  const int bb = blockIdx.x & 15;
  const int s  = blockIdx.x >> 4;

  // ---- prologue P1: stage hs (f16) + Ws1 slice ----
  for (int idx = tid; idx < 24576; idx += 1024) {
    int tp = idx >> 7, k2 = idx & 127;
    const float* hp = &hsB[(bb * 192 + tp) * 256 + 2 * k2];
    hsL[tp * 129 + k2] = packh2(hp[0], hp[1]);
  }
  for (int idx = tid; idx < 4096; idx += 1024) {
    int c = idx >> 7, k2 = idx & 127;
    const float* wp = &Ws_w[(32 * s + c) * 768 + 2 * k2];
    Ws1L[c * 129 + k2] = packh2(wp[0], wp[1]);
  }
  __syncthreads();
  // ---- P2: base_s = xb3 + hs @ Ws1^T for [192 tp][own 32 c] ----
  {
    int c = tid & 31, g = tid >> 5;
    float a6[6];
    #pragma unroll
    for (int j = 0; j < 6; ++j)
      a6[j] = xb3[((g * 6 + j) * 16 + bb) * 256 + 32 * s + c];
    for (int k2 = 0; k2 < 128; ++k2) {
      unsigned wv = Ws1L[c * 129 + k2];
      #pragma unroll
      for (int j = 0; j < 6; ++j)
        a6[j] = fdot2(wv, hsL[(g * 6 + j) * 129 + k2], a6[j]);
    }
    #pragma unroll
    for (int j = 0; j < 6; ++j)
      baseS[(g * 6 + j) * 33 + c] = a6[j];
  }
  __syncthreads();
  // ---- P3: persistent registers: base (f16 pairs), hs for R ----
  unsigned bs4[4] = {0u, 0u, 0u, 0u};
  if (tid < 768) {
    int tp = tid >> 2, q = tid & 3;
    #pragma unroll
    for (int j2 = 0; j2 < 4; ++j2)
      bs4[j2] = packh2(baseS[tp * 33 + q * 8 + 2 * j2],
                       baseS[tp * 33 + q * 8 + 2 * j2 + 1]);
  }
  float hsr[6];
  {
    int c = tid & 31, g = tid >> 5;
    #pragma unroll
    for (int j = 0; j < 6; ++j)
      hsr[j] = hsB[(bb * 192 + g * 6 + j) * 256 + 32 * s + c];
  }
  __syncthreads();
  // ---- P4: main weight fills (overwrite prologue regions) ----
  for (int idx = tid; idx < 32768; idx += 1024) {
    int j = idx & 3, l = (idx >> 2) & 127, k2q = idx >> 9;
    int k2 = k2q * 4 + j;
    int row = (l >> 5) * 256 + 32 * s + (l & 31);
    const float* wp = &Wc[row * 768 + 256 + 2 * k2];
    WcH[idx] = packh2(wp[0], wp[1]);
  }
  for (int idx = tid; idx < 4096; idx += 1024) {
    int c = idx >> 7, k2 = idx & 127;
    const float* wp = &Ws_w[(32 * s + c) * 768 + 256 + 2 * k2];
    Ws2L[c * 130 + k2] = packh2(wp[0], wp[1]);
  }
  if (tid < 32) usl[tid] = Us_w[32 * s + tid];
  const float usb = Us_b[0];
  __syncthreads();

  u64* Pb = Pbuf + (bb * 8) * 192;
  u64* Rb = Rbuf + bb * 256;
  u64* Hb = Hbuf + bb * 256;
  const uint4* wp4 = (const uint4*)WcH;
  const uint4* av4 = (const uint4*)actH;
  float creg = 0.f;       // c-state (tid<32)

  for (int t = 0; t < T_LEN; ++t) {
    const unsigned seq = (unsigned)(t + 1);
    float xp0 = 0.f, xp1 = 0.f, xp2 = 0.f, xp3 = 0.f;
    if (tid < 32) {
      const float* xq = &xpre[(t * 16 + bb) * 1024 + 32 * s + tid];
      xp0 = xq[0]; xp1 = xq[256]; xp2 = xq[512]; xp3 = xq[768];
    }
    // S1: h(t-1) poll (single u64 per thread)
    if (tid < 256) {
      float hvv = 0.f;
      if (t > 0) {
        u64 v;
        do { v = gld64(&Hb[tid]); } while ((unsigned)v != (unsigned)t);
        hvv = __uint_as_float((unsigned)(v >> 32));
      }
      hl[tid] = hvv;
    }
    __syncthreads();                 // B1
    if (tid < 128) {
      unsigned u = packh2(hl[2 * tid], hl[2 * tid + 1]);
      h2l[tid] = u; actH[128 + tid] = u;
    }
    __syncthreads();                 // B2
    // S3: hterm_s = Ws2[c-slice,:] @ h  (local, no exchange)
    {
      int c = tid & 31, seg = tid >> 5;
      float a = 0.f;
      #pragma unroll
      for (int i = 0; i < 4; ++i)
        a = fdot2(Ws2L[c * 130 + seg * 4 + i], h2l[seg * 4 + i], a);
      scr[c * 33 + seg] = a;
    }
    __syncthreads();                 // B3
    if (tid < 32) {
      float a = 0.f;
      #pragma unroll 8
      for (int i = 0; i < 32; ++i) a += scr[tid * 33 + i];
      hterml[tid] = a;
    }
    __syncthreads();                 // B4
    // S5: score partials over own 32 c for all 192 tp; publish p_s
    if (tid < 768) {
      int tp = tid >> 2, q = tid & 3;
      float p = 0.f;
      #pragma unroll
      for (int m = 0; m < 4; ++m) {
        float2 bv = unp2(bs4[m]);
        int c0 = q * 8 + 2 * m;
        p += usl[c0]     * tanh_f(bv.x + hterml[c0]);
        p += usl[c0 + 1] * tanh_f(bv.y + hterml[c0 + 1]);
      }
      p += __shfl_xor(p, 1);
      p += __shfl_xor(p, 2);
      if ((tid & 3) == 0)
        gst64(&Pb[s * 192 + tp], ((u64)__float_as_uint(p) << 32) | seq);
    }
    // S6: p poll + exp (bounded scores, no max-sub)
    if (tid < 192) {
      u64 v[8];
      for (;;) {
        bool ok = true;
        #pragma unroll
        for (int sp = 0; sp < 8; ++sp) {
          v[sp] = gld64(&Pb[sp * 192 + tid]);
          ok &= ((unsigned)v[sp] == seq);
        }
        if (ok) break;
      }
      float sum = 0.f;
      #pragma unroll
      for (int sp = 0; sp < 8; ++sp) sum += __uint_as_float((unsigned)(v[sp] >> 32));
      eel[tid] = __expf(sum + usb);
    }
    __syncthreads();                 // B5
    // S7: L-reduce (wave0) + R partial (all, hs in regs)
    if (tid < 64) {
      float a = eel[tid] + eel[tid + 64] + eel[tid + 128];
      #pragma unroll
      for (int off = 32; off >= 1; off >>= 1) a += __shfl_xor(a, off);
      if (tid == 0) msc[0] = 1.f / a;
    }
    {
      int c = tid & 31, g = tid >> 5;
      float a = 0.f;
      #pragma unroll
      for (int j = 0; j < 6; ++j) a = fmaf(eel[g * 6 + j], hsr[j], a);
      scr[g * 33 + c] = a;
    }
    __syncthreads();                 // B6
    if (tid < 32) {
      float a = 0.f;
      #pragma unroll 8
      for (int g = 0; g < 32; ++g) a += scr[g * 33 + tid];
      a *= msc[0];                   // final normalized R slice
      gst64(&Rb[32 * s + tid], ((u64)__float_as_uint(a) << 32) | seq);
    }
    // S9: R poll (1 u64/thread)
    if (tid < 256) {
      u64 v;
      do { v = gld64(&Rb[tid]); } while ((unsigned)v != seq);
      rl[tid] = __uint_as_float((unsigned)(v >> 32));
    }
    __syncthreads();                 // B7
    if (tid < 128) actH[tid] = packh2(rl[2 * tid], rl[2 * tid + 1]);
    __syncthreads();                 // B8
    // S11: gates GEMV (K=512 f16): l = tid&127, K-eighth = tid>>7
    {
      int l = tid & 127, kq = tid >> 7;
      float a = 0.f;
      #pragma unroll
      for (int i = 0; i < 8; ++i) {
        uint4 w4 = wp4[(kq * 8 + i) * 128 + l];
        uint4 a4 = av4[kq * 8 + i];
        a = fdot2(w4.x, a4.x, a); a = fdot2(w4.y, a4.y, a);
        a = fdot2(w4.z, a4.z, a); a = fdot2(w4.w, a4.w, a);
      }
      prel[l * 8 + kq] = a;
    }
    __syncthreads();                 // B9
    if (tid < 32) {
      float pr[4];
      #pragma unroll
      for (int g = 0; g < 4; ++g) {
        const float4* pp = (const float4*)&prel[(g * 32 + tid) * 8];
        float4 p0 = pp[0], p1 = pp[1];
        pr[g] = p0.x + p0.y + p0.z + p0.w + p1.x + p1.y + p1.z + p1.w;
      }
      pr[0] += xp0; pr[1] += xp1; pr[2] += xp2; pr[3] += xp3;
      float cn = fmaf(sigm(pr[1]), creg, sigm(pr[0]) * tanh_f(pr[2]));
      float hh = sigm(pr[3]) * tanh_f(cn);
      creg = cn;
      out[(bb * 192 + t) * 256 + 32 * s + tid] = hh;
      gst64(&Hb[32 * s + tid], ((u64)__float_as_uint(hh) << 32) | seq);
    }
  }
}

extern "C" void kernel_launch(void* const* d_in, const int* in_sizes, int n_in,
                              void* d_out, int out_size, void* d_ws, size_t ws_size,
                              hipStream_t stream) {
  (void)in_sizes; (void)n_in; (void)out_size; (void)ws_size;
  const float* x    = (const float*)d_in[0];
  const float* W_ih = (const float*)d_in[1];
  const float* W_hh = (const float*)d_in[2];
  const float* b_l  = (const float*)d_in[3];
  const float* Ws_w = (const float*)d_in[4];
  const float* Ws_b = (const float*)d_in[5];
  const float* Us_w = (const float*)d_in[6];
  const float* Us_b = (const float*)d_in[7];
  const float* Wc   = (const float*)d_in[8];
  const float* bc   = (const float*)d_in[9];
  float* out = (float*)d_out;
  float* ws = (float*)d_ws;

  hipFuncSetAttribute((const void*)task_kernel,
                      hipFuncAttributeMaxDynamicSharedMemorySize, 160 * 1024);

  // zero exchange region (P, R, H, HX, ticket — seq tags restart each launch)
  initk<<<64, 256, 0, stream>>>(ws + OFF_P, EXCH_WORDS);

  // fused x-projections: X1F, xpre, xb3
  proj3<<<dim3(72, 192), 256, 0, stream>>>(x, W_ih, b_l, Wc, bc, Ws_w, Ws_b, ws);

  // shared LSTM: 16 candidate blocks, 2 elected same-XCD workers, W_hh in VGPRs
  lstm_kernel<<<16, 512, 0, stream>>>(ws + OFF_X1F, W_hh, ws + OFF_HSB,
                                      (u64*)(ws + OFF_HX),
                                      (unsigned*)(ws + OFF_TICKET));

  // task loop
  task_kernel<<<128, 1024, SMEM_TASK, stream>>>(
      ws + OFF_XB3, ws + OFF_XPRE, ws + OFF_HSB, Us_w, Us_b, Wc, Ws_w,
      (u64*)(ws + OFF_P), (u64*)(ws + OFF_R), (u64*)(ws + OFF_H), out);
}

// Round 3
// 1788.740 us; speedup vs baseline: 1.3162x; 1.0899x over previous
//
#include <hip/hip_runtime.h>
#include <hip/hip_fp16.h>

#define T_LEN 192

typedef unsigned long long u64;
typedef _Float16 f16x8 __attribute__((ext_vector_type(8)));
typedef float f32x4 __attribute__((ext_vector_type(4)));

// ws float offsets
#define OFF_X1F   0          // X1F [192][64 tile][16 b][16 row] f32
#define OFF_XPRE  3145728    // [192][16][1024]
#define OFF_XB3   6291456    // x@Ws3 + Ws_b  [192][16][256]
#define OFF_HSB   7077888    // hsB [16][192][256]
#define OFF_P     7864320    // u64 [16][8][192]
#define OFF_R     7913472    // u64 [16][256] (unused, kept for layout)
#define OFF_H     7921664    // u64 [16][256]
#define OFF_HX    7929856    // u64 [2][256][16]
#define EXCH_WORDS 81920

// task LDS: G2 ends at 99072 + 128*97*4 = 148736
#define SMEM_TASK 148736

__device__ __forceinline__ unsigned packh2(float a, float b){
  union { __half2 h; unsigned u; } v;
  v.h = __halves2half2(__float2half(a), __float2half(b));
  return v.u;
}
__device__ __forceinline__ float2 unp2(unsigned u){
  union { unsigned u32; __half2 h; } v; v.u32 = u;
  return __half22float2(v.h);
}
__device__ __forceinline__ float fdot2(unsigned a, unsigned b, float c){
#if __has_builtin(__builtin_amdgcn_fdot2)
  typedef _Float16 h2t __attribute__((ext_vector_type(2)));
  union { unsigned u; h2t h; } ua, ub;
  ua.u = a; ub.u = b;
  return __builtin_amdgcn_fdot2(ua.h, ub.h, c, false);
#else
  float2 x = unp2(a), y = unp2(b);
  return c + x.x*y.x + x.y*y.y;
#endif
}
__device__ __forceinline__ float tanh_f(float x){
  float cx = fminf(fmaxf(x, -15.f), 15.f);
  float e = __expf(2.f * cx);
  return (e - 1.f) / (e + 1.f);
}
__device__ __forceinline__ float sigm(float x){
  float cx = fminf(fmaxf(x, -30.f), 30.f);
  return 1.f / (1.f + __expf(-cx));
}

__device__ __forceinline__ u64 gld64(const u64* p){
  return __hip_atomic_load(p, __ATOMIC_RELAXED, __HIP_MEMORY_SCOPE_AGENT);
}
__device__ __forceinline__ void gst64(u64* p, u64 v){
  __hip_atomic_store(p, v, __ATOMIC_RELAXED, __HIP_MEMORY_SCOPE_AGENT);
}

__global__ __launch_bounds__(256) void initk(float* p, int n){
  int i = blockIdx.x * blockDim.x + threadIdx.x;
  int stride = gridDim.x * blockDim.x;
  for (; i < n; i += stride) p[i] = 0.f;
}

// fused x-projections: bx<32 -> X1F (MFMA-fragment layout), bx<64 -> xpre, else xb3
__global__ __launch_bounds__(256) void proj3(const float* __restrict__ x,
                                             const float* __restrict__ W_ih,
                                             const float* __restrict__ b_l,
                                             const float* __restrict__ Wc,
                                             const float* __restrict__ bc,
                                             const float* __restrict__ Ws_w,
                                             const float* __restrict__ Ws_b,
                                             float* __restrict__ ws){
  __shared__ float As[16 * 258];
  __shared__ float Wsh[256 * 34];
  const int bx = blockIdx.x, t = blockIdx.y, tid = threadIdx.x;
  const float* W; const float* bias; int ldw, woff, c0, mode; float* out;
  if (bx < 32)      { W = W_ih; bias = b_l;  ldw = 256; woff = 0;   c0 = bx * 32;        mode = 0; out = ws + OFF_X1F; }
  else if (bx < 64) { W = Wc;   bias = bc;   ldw = 768; woff = 0;   c0 = (bx - 32) * 32; mode = 1; out = ws + OFF_XPRE; }
  else              { W = Ws_w; bias = Ws_b; ldw = 768; woff = 512; c0 = (bx - 64) * 32; mode = 2; out = ws + OFF_XB3; }

  for (int i = 0; i < 16; ++i)
    As[i * 258 + tid] = x[(t * 16 + i) * 256 + tid];
  for (int i = 0; i < 32; ++i)
    Wsh[tid * 34 + i] = W[(c0 + i) * ldw + woff + tid];
  __syncthreads();

  const int r = tid >> 4;          // batch row within t
  const int c2 = (tid & 15) * 2;
  float acc0 = 0.f, acc1 = 0.f;
  for (int k = 0; k < 256; k += 2) {
    float2 a  = *(const float2*)&As[r * 258 + k];
    float2 w0 = *(const float2*)&Wsh[k * 34 + c2];
    float2 w1 = *(const float2*)&Wsh[(k + 1) * 34 + c2];
    acc0 = fmaf(a.x, w0.x, acc0); acc0 = fmaf(a.y, w1.x, acc0);
    acc1 = fmaf(a.x, w0.y, acc1); acc1 = fmaf(a.y, w1.y, acc1);
  }
  const int cg = c0 + c2;
  acc0 += bias[cg]; acc1 += bias[cg + 1];
  float2 res; res.x = acc0; res.y = acc1;
  if (mode == 0) {
    *(float2*)&out[((t * 64 + (cg >> 4)) * 16 + r) * 16 + (cg & 15)] = res;
  } else if (mode == 1) {
    *(float2*)&out[(t * 16 + r) * 1024 + cg] = res;
  } else {
    *(float2*)&out[(t * 16 + r) * 256 + cg] = res;
  }
}

// Shared LSTM: 2 WGs x 512 thr; W_hh resident in VGPRs, MFMA 16x16x32_f16.
// (round-0 proven version; XCD election experiment reverted — no measurable gain)
__global__ __launch_bounds__(512) void lstm_kernel(const float* __restrict__ X1F,
                                                   const float* __restrict__ W_hh,
                                                   float* __restrict__ hsB,
                                                   u64* __restrict__ hx){
  __shared__ unsigned hT[16 * 136];   // [b][k2], row stride 136 u32 (16B-aligned)
  const int tid = threadIdx.x;
  const int wg = blockIdx.x;
  const int wave = tid >> 6, lane = tid & 63;
  const int b16 = lane & 15, quad = lane >> 4;
  const int jb = wg * 8 + wave;       // j-block 0..15
  const int peer0 = (1 - wg) * 128;

  // W fragments -> VGPRs (once)
  f16x8 wf[4][8];
  #pragma unroll
  for (int g = 0; g < 4; ++g) {
    #pragma unroll
    for (int kk = 0; kk < 8; ++kk) {
      int row = g * 256 + jb * 16 + b16;
      const float* wp = &W_hh[row * 256 + kk * 32 + quad * 8];
      f16x8 v;
      #pragma unroll
      for (int j = 0; j < 8; ++j) v[j] = (_Float16)wp[j];
      wf[g][kk] = v;
    }
  }
  for (int i = tid; i < 16 * 136; i += 512) hT[i] = 0u;
  float cst[4] = {0.f, 0.f, 0.f, 0.f};
  __syncthreads();

  for (int t = 0; t < T_LEN; ++t) {
    float4 xi[4];
    #pragma unroll
    for (int g = 0; g < 4; ++g)
      xi[g] = *(const float4*)&X1F[((t * 64 + g * 16 + jb) * 16 + b16) * 16 + quad * 4];

    if (t > 0) {
      const u64* src = &hx[((u64)((t - 1) & 1) * 256) * 16];
      #pragma unroll
      for (int cc = 0; cc < 2; ++cc) {
        int idx = tid * 2 + cc;
        int jp = idx >> 4, bbq = idx & 15;
        int j0 = peer0 + jp * 2;
        u64 v0, v1;
        for (;;) {
          v0 = gld64(&src[(j0) * 16 + bbq]);
          v1 = gld64(&src[(j0 + 1) * 16 + bbq]);
          if ((unsigned)v0 == (unsigned)t && (unsigned)v1 == (unsigned)t) break;
        }
        hT[bbq * 136 + (j0 >> 1)] =
            packh2(__uint_as_float((unsigned)(v0 >> 32)),
                   __uint_as_float((unsigned)(v1 >> 32)));
      }
    }
    __syncthreads();

    f32x4 acc[4];
    #pragma unroll
    for (int g = 0; g < 4; ++g) {
      f32x4 a; a[0]=xi[g].x; a[1]=xi[g].y; a[2]=xi[g].z; a[3]=xi[g].w;
      acc[g] = a;
    }
    #pragma unroll
    for (int kk = 0; kk < 8; ++kk) {
      union { uint4 u; f16x8 h; } bv;
      bv.u = *(const uint4*)&hT[b16 * 136 + kk * 16 + quad * 4];
      #pragma unroll
      for (int g = 0; g < 4; ++g)
        acc[g] = __builtin_amdgcn_mfma_f32_16x16x32_f16(wf[g][kk], bv.h, acc[g], 0, 0, 0);
    }
    __syncthreads();

    float hv[4];
    #pragma unroll
    for (int r = 0; r < 4; ++r) {
      float pi = acc[0][r], pf = acc[1][r], pg = acc[2][r], po = acc[3][r];
      float cn = fmaf(sigm(pf), cst[r], sigm(pi) * tanh_f(pg));
      hv[r] = sigm(po) * tanh_f(cn);
      cst[r] = cn;
    }
    int j0 = jb * 16 + quad * 4;
    *(float4*)&hsB[(b16 * 192 + t) * 256 + j0] = make_float4(hv[0], hv[1], hv[2], hv[3]);
    hT[b16 * 136 + (j0 >> 1)]     = packh2(hv[0], hv[1]);
    hT[b16 * 136 + (j0 >> 1) + 1] = packh2(hv[2], hv[3]);
    u64* dst = &hx[((u64)(t & 1) * 256) * 16];
    #pragma unroll
    for (int r = 0; r < 4; ++r)
      gst64(&dst[(j0 + r) * 16 + b16],
            ((u64)__float_as_uint(hv[r]) << 32) | (unsigned)(t + 1));
  }
}

// Task loop: 128 WGs x 1024 thr; b = bid&15, s = bid>>4 owns c in [32s,32s+32).
// R-EXCHANGE ELIMINATED: G[t][l] = Wc_R[l,:] @ hs[bb][t,:] precomputed per WG;
// per-step R-contribution = msc * sum_t eel_t * G[t][l] (WG-local after p-poll).
// 2 exchanges/step (p, h), 5 barriers/step.
__global__ __launch_bounds__(1024) void task_kernel(
    const float* __restrict__ xb3, const float* __restrict__ xpre,
    const float* __restrict__ hsB, const float* __restrict__ Us_w,
    const float* __restrict__ Us_b, const float* __restrict__ Wc,
    const float* __restrict__ Ws_w,
    u64* __restrict__ Pbuf, u64* __restrict__ Hbuf,
    float* __restrict__ out){
  extern __shared__ char smem[];
  // prologue views (all dead before their region is overwritten)
  unsigned* hsL  = (unsigned*)smem;               // [192][129] u32 (f16x2)
  unsigned* Ws1L = (unsigned*)(smem + 99072);     // [32][129]  (inside G2 region)
  float*    baseS= (float*)(smem + 115584);       // [192][33]  (inside G2 region)
  // main views
  unsigned* WcH  = (unsigned*)smem;               // 16384 u32: Wc h-part f16 pairs
  unsigned* Ws2L = (unsigned*)(smem + 65536);     // [32][130]
  float* scr     = (float*)(smem + 82176);        // [32][33]
  float* prel    = (float*)(smem + 82176);        // [128][8] (disjoint phase)
  float* eel     = (float*)(smem + 86400);        // 192
  unsigned* h2l  = (unsigned*)(smem + 87168);     // 128
  unsigned* actH = (unsigned*)(smem + 87680);     // 128 (h pairs)
  float* hterml  = (float*)(smem + 88192);        // 32
  float* usl     = (float*)(smem + 88320);        // 32
  float* msc     = (float*)(smem + 88448);        // 1
  unsigned* G2   = (unsigned*)(smem + 99072);     // [128][97] u32 (padded stride)

  const int tid = threadIdx.x;
  const int bb = blockIdx.x & 15;
  const int s  = blockIdx.x >> 4;

  // ---- P1: stage hs (f16) + Ws1 slice ----
  for (int idx = tid; idx < 24576; idx += 1024) {
    int tp = idx >> 7, k2 = idx & 127;
    const float* hp = &hsB[(bb * 192 + tp) * 256 + 2 * k2];
    hsL[tp * 129 + k2] = packh2(hp[0], hp[1]);
  }
  for (int idx = tid; idx < 4096; idx += 1024) {
    int c = idx >> 7, k2 = idx & 127;
    const float* wp = &Ws_w[(32 * s + c) * 768 + 2 * k2];
    Ws1L[c * 129 + k2] = packh2(wp[0], wp[1]);
  }
  __syncthreads();
  // ---- P2: base_s = xb3 + hs @ Ws1^T for [192 tp][own 32 c] ----
  {
    int c = tid & 31, g = tid >> 5;
    float a6[6];
    #pragma unroll
    for (int j = 0; j < 6; ++j)
      a6[j] = xb3[((g * 6 + j) * 16 + bb) * 256 + 32 * s + c];
    for (int k2 = 0; k2 < 128; ++k2) {
      unsigned wv = Ws1L[c * 129 + k2];
      #pragma unroll
      for (int j = 0; j < 6; ++j)
        a6[j] = fdot2(wv, hsL[(g * 6 + j) * 129 + k2], a6[j]);
    }
    #pragma unroll
    for (int j = 0; j < 6; ++j)
      baseS[(g * 6 + j) * 33 + c] = a6[j];
  }
  __syncthreads();
  // ---- P3a: persistent base registers (f16 pairs) ----
  unsigned bs4[4] = {0u, 0u, 0u, 0u};
  if (tid < 768) {
    int tp = tid >> 2, q = tid & 3;
    #pragma unroll
    for (int j2 = 0; j2 < 4; ++j2)
      bs4[j2] = packh2(baseS[tp * 33 + q * 8 + 2 * j2],
                       baseS[tp * 33 + q * 8 + 2 * j2 + 1]);
  }
  __syncthreads();
  // ---- P3b: G2[l][j] = f16 pairs over t of (Wc_R[l,:] @ hs[t,:]) ----
  {
    int l = tid & 127, tg = tid >> 7;   // tg in [0,8): 24 t's each
    int row = (l >> 5) * 256 + 32 * s + (l & 31);
    const float* wr = &Wc[row * 768 + 256];   // R-part cols
    float acc[24];
    #pragma unroll
    for (int i = 0; i < 24; ++i) acc[i] = 0.f;
    for (int kc = 0; kc < 128; kc += 16) {
      unsigned wv[16];
      #pragma unroll
      for (int i = 0; i < 16; ++i) {
        float2 wp2 = *(const float2*)&wr[2 * (kc + i)];
        wv[i] = packh2(wp2.x, wp2.y);
      }
      #pragma unroll
      for (int tt = 0; tt < 24; ++tt) {
        const unsigned* hp = &hsL[(tg * 24 + tt) * 129 + kc];
        float a = acc[tt];
        #pragma unroll
        for (int i = 0; i < 16; ++i) a = fdot2(wv[i], hp[i], a);
        acc[tt] = a;
      }
    }
    #pragma unroll
    for (int i = 0; i < 12; ++i)
      G2[l * 97 + tg * 12 + i] = packh2(acc[2 * i], acc[2 * i + 1]);
  }
  __syncthreads();
  // ---- P4: main weight fills (overwrite hsL region) ----
  for (int idx = tid; idx < 16384; idx += 1024) {
    int j = idx & 3, l = (idx >> 2) & 127, k2q = idx >> 9;   // k2q in [0,32)
    int k2 = k2q * 4 + j;                                    // [0,128)
    int row = (l >> 5) * 256 + 32 * s + (l & 31);
    const float* wp = &Wc[row * 768 + 512 + 2 * k2];         // h-part cols
    WcH[idx] = packh2(wp[0], wp[1]);
  }
  for (int idx = tid; idx < 4096; idx += 1024) {
    int c = idx >> 7, k2 = idx & 127;
    const float* wp = &Ws_w[(32 * s + c) * 768 + 256 + 2 * k2];
    Ws2L[c * 130 + k2] = packh2(wp[0], wp[1]);
  }
  if (tid < 32) usl[tid] = Us_w[32 * s + tid];
  const float usb = Us_b[0];
  __syncthreads();

  u64* Pb = Pbuf + (bb * 8) * 192;
  u64* Hb = Hbuf + bb * 256;
  const uint4* wp4 = (const uint4*)WcH;
  const uint4* av4 = (const uint4*)actH;
  float creg = 0.f;       // c-state (tid<32)

  for (int t = 0; t < T_LEN; ++t) {
    const unsigned seq = (unsigned)(t + 1);
    float xp0 = 0.f, xp1 = 0.f, xp2 = 0.f, xp3 = 0.f;
    if (tid < 32) {
      const float* xq = &xpre[(t * 16 + bb) * 1024 + 32 * s + tid];
      xp0 = xq[0]; xp1 = xq[256]; xp2 = xq[512]; xp3 = xq[768];
    }
    // S1: h(t-1) poll + in-wave pack (shfl) — one phase, one barrier
    if (tid < 256) {
      float hvv = 0.f;
      if (t > 0) {
        u64 v;
        do { v = gld64(&Hb[tid]); } while ((unsigned)v != (unsigned)t);
        hvv = __uint_as_float((unsigned)(v >> 32));
      }
      float hp_ = __shfl_xor(hvv, 1);
      if ((tid & 1) == 0) {
        unsigned u = packh2(hvv, hp_);
        h2l[tid >> 1] = u; actH[tid >> 1] = u;
      }
    }
    __syncthreads();                 // B1
    // S3: hterm partials = Ws2[c,:] @ h
    {
      int c = tid & 31, seg = tid >> 5;
      float a = 0.f;
      #pragma unroll
      for (int i = 0; i < 4; ++i)
        a = fdot2(Ws2L[c * 130 + seg * 4 + i], h2l[seg * 4 + i], a);
      scr[c * 33 + seg] = a;
    }
    __syncthreads();                 // B3
    if (tid < 32) {
      float a = 0.f;
      #pragma unroll 8
      for (int i = 0; i < 32; ++i) a += scr[tid * 33 + i];
      hterml[tid] = a;
    }
    __syncthreads();                 // B4
    // S5: score partials over own 32 c for all 192 tp; publish p_s
    if (tid < 768) {
      int tp = tid >> 2, q = tid & 3;
      float p = 0.f;
      #pragma unroll
      for (int m = 0; m < 4; ++m) {
        float2 bv = unp2(bs4[m]);
        int c0 = q * 8 + 2 * m;
        p += usl[c0]     * tanh_f(bv.x + hterml[c0]);
        p += usl[c0 + 1] * tanh_f(bv.y + hterml[c0 + 1]);
      }
      p += __shfl_xor(p, 1);
      p += __shfl_xor(p, 2);
      if ((tid & 3) == 0)
        gst64(&Pb[s * 192 + tp], ((u64)__float_as_uint(p) << 32) | seq);
    }
    // S6: p poll + exp (bounded scores, no max-sub)
    if (tid < 192) {
      u64 v[8];
      for (;;) {
        bool ok = true;
        #pragma unroll
        for (int sp = 0; sp < 8; ++sp) {
          v[sp] = gld64(&Pb[sp * 192 + tid]);
          ok &= ((unsigned)v[sp] == seq);
        }
        if (ok) break;
      }
      float sum = 0.f;
      #pragma unroll
      for (int sp = 0; sp < 8; ++sp) sum += __uint_as_float((unsigned)(v[sp] >> 32));
      eel[tid] = __expf(sum + usb);
    }
    __syncthreads();                 // B5
    // S7: msc reduce (wave0, extra duty) — visible to all after B9
    if (tid < 64) {
      float aa = eel[tid] + eel[tid + 64] + eel[tid + 128];
      #pragma unroll
      for (int off = 32; off >= 1; off >>= 1) aa += __shfl_xor(aa, off);
      if (tid == 0) msc[0] = 1.f / aa;
    }
    // S11: gates partials — lanes kq<4: Wc_h @ h (K=256); kq>=4: sum_t eel_t G[t]
    {
      int l = tid & 127, kq = tid >> 7;
      float a = 0.f;
      if (kq < 4) {
        #pragma unroll
        for (int i = 0; i < 8; ++i) {
          uint4 w4 = wp4[(kq * 8 + i) * 128 + l];
          uint4 a4 = av4[kq * 8 + i];
          a = fdot2(w4.x, a4.x, a); a = fdot2(w4.y, a4.y, a);
          a = fdot2(w4.z, a4.z, a); a = fdot2(w4.w, a4.w, a);
        }
      } else {
        int l4 = kq - 4;
        const unsigned* gp = &G2[l * 97 + l4 * 24];
        const float2* ep = (const float2*)&eel[l4 * 48];
        #pragma unroll
        for (int i = 0; i < 24; ++i) {
          float2 g = unp2(gp[i]);
          float2 e = ep[i];
          a = fmaf(g.x, e.x, a); a = fmaf(g.y, e.y, a);
        }
      }
      prel[l * 8 + kq] = a;
    }
    __syncthreads();                 // B9
    if (tid < 32) {
      float m = msc[0];
      float pr[4];
      #pragma unroll
      for (int g = 0; g < 4; ++g) {
        const float4* pp = (const float4*)&prel[(g * 32 + tid) * 8];
        float4 p0 = pp[0], p1 = pp[1];
        pr[g] = (p0.x + p0.y + p0.z + p0.w) + m * (p1.x + p1.y + p1.z + p1.w);
      }
      pr[0] += xp0; pr[1] += xp1; pr[2] += xp2; pr[3] += xp3;
      float cn = fmaf(sigm(pr[1]), creg, sigm(pr[0]) * tanh_f(pr[2]));
      float hh = sigm(pr[3]) * tanh_f(cn);
      creg = cn;
      out[(bb * 192 + t) * 256 + 32 * s + tid] = hh;
      gst64(&Hb[32 * s + tid], ((u64)__float_as_uint(hh) << 32) | seq);
    }
  }
}

extern "C" void kernel_launch(void* const* d_in, const int* in_sizes, int n_in,
                              void* d_out, int out_size, void* d_ws, size_t ws_size,
                              hipStream_t stream) {
  (void)in_sizes; (void)n_in; (void)out_size; (void)ws_size;
  const float* x    = (const float*)d_in[0];
  const float* W_ih = (const float*)d_in[1];
  const float* W_hh = (const float*)d_in[2];
  const float* b_l  = (const float*)d_in[3];
  const float* Ws_w = (const float*)d_in[4];
  const float* Ws_b = (const float*)d_in[5];
  const float* Us_w = (const float*)d_in[6];
  const float* Us_b = (const float*)d_in[7];
  const float* Wc   = (const float*)d_in[8];
  const float* bc   = (const float*)d_in[9];
  float* out = (float*)d_out;
  float* ws = (float*)d_ws;

  hipFuncSetAttribute((const void*)task_kernel,
                      hipFuncAttributeMaxDynamicSharedMemorySize, 160 * 1024);

  // zero exchange region (P, R, H, HX — seq tags restart at 1 each launch)
  initk<<<64, 256, 0, stream>>>(ws + OFF_P, EXCH_WORDS);

  // fused x-projections: X1F, xpre, xb3
  proj3<<<dim3(72, 192), 256, 0, stream>>>(x, W_ih, b_l, Wc, bc, Ws_w, Ws_b, ws);

  // shared LSTM: 2 persistent WGs, W_hh in VGPRs via MFMA
  lstm_kernel<<<2, 512, 0, stream>>>(ws + OFF_X1F, W_hh, ws + OFF_HSB,
                                     (u64*)(ws + OFF_HX));

  // task loop (R-exchange-free)
  task_kernel<<<128, 1024, SMEM_TASK, stream>>>(
      ws + OFF_XB3, ws + OFF_XPRE, ws + OFF_HSB, Us_w, Us_b, Wc, Ws_w,
      (u64*)(ws + OFF_P), (u64*)(ws + OFF_H), out);
}

// Round 4
// 1712.652 us; speedup vs baseline: 1.3747x; 1.0444x over previous
//
#include <hip/hip_runtime.h>
#include <hip/hip_fp16.h>

#define T_LEN 192

typedef unsigned long long u64;
typedef _Float16 f16x8 __attribute__((ext_vector_type(8)));
typedef float f32x4 __attribute__((ext_vector_type(4)));

// ws float offsets
#define OFF_X1F   0          // X1F [192][64 tile][16 b][16 row] f32
#define OFF_XPRE  3145728    // [192][16][1024]
#define OFF_XB3   6291456    // x@Ws3 + Ws_b  [192][16][256]
#define OFF_HSB   7077888    // hsB [16][192][256]
#define OFF_P     7864320    // u64 [16][8][192]
#define OFF_H     7921664    // u64 [16][256]
#define OFF_HX    7929856    // u64 [2][128][16] (lstm pair exchange)
#define OFF_HP    7946240    // u64 [16][8][256] (hterm partials)
#define EXCH_WORDS 147456    // OFF_P .. OFF_HP+65536

#define SMEM_TASK 148736

__device__ __forceinline__ unsigned packh2(float a, float b){
  union { __half2 h; unsigned u; } v;
  v.h = __halves2half2(__float2half(a), __float2half(b));
  return v.u;
}
__device__ __forceinline__ float2 unp2(unsigned u){
  union { unsigned u32; __half2 h; } v; v.u32 = u;
  return __half22float2(v.h);
}
__device__ __forceinline__ float fdot2(unsigned a, unsigned b, float c){
#if __has_builtin(__builtin_amdgcn_fdot2)
  typedef _Float16 h2t __attribute__((ext_vector_type(2)));
  union { unsigned u; h2t h; } ua, ub;
  ua.u = a; ub.u = b;
  return __builtin_amdgcn_fdot2(ua.h, ub.h, c, false);
#else
  float2 x = unp2(a), y = unp2(b);
  return c + x.x*y.x + x.y*y.y;
#endif
}
__device__ __forceinline__ float tanh_f(float x){
  float cx = fminf(fmaxf(x, -15.f), 15.f);
  float e = __expf(2.f * cx);
  return (e - 1.f) / (e + 1.f);
}
__device__ __forceinline__ float sigm(float x){
  float cx = fminf(fmaxf(x, -30.f), 30.f);
  return 1.f / (1.f + __expf(-cx));
}

__device__ __forceinline__ u64 gld64(const u64* p){
  return __hip_atomic_load(p, __ATOMIC_RELAXED, __HIP_MEMORY_SCOPE_AGENT);
}
__device__ __forceinline__ void gst64(u64* p, u64 v){
  __hip_atomic_store(p, v, __ATOMIC_RELAXED, __HIP_MEMORY_SCOPE_AGENT);
}

__global__ __launch_bounds__(256) void initk(float* p, int n){
  int i = blockIdx.x * blockDim.x + threadIdx.x;
  int stride = gridDim.x * blockDim.x;
  for (; i < n; i += stride) p[i] = 0.f;
}

// fused x-projections: bx<32 -> X1F (MFMA-fragment layout), bx<64 -> xpre, else xb3
__global__ __launch_bounds__(256) void proj3(const float* __restrict__ x,
                                             const float* __restrict__ W_ih,
                                             const float* __restrict__ b_l,
                                             const float* __restrict__ Wc,
                                             const float* __restrict__ bc,
                                             const float* __restrict__ Ws_w,
                                             const float* __restrict__ Ws_b,
                                             float* __restrict__ ws){
  __shared__ float As[16 * 258];
  __shared__ float Wsh[256 * 34];
  const int bx = blockIdx.x, t = blockIdx.y, tid = threadIdx.x;
  const float* W; const float* bias; int ldw, woff, c0, mode; float* out;
  if (bx < 32)      { W = W_ih; bias = b_l;  ldw = 256; woff = 0;   c0 = bx * 32;        mode = 0; out = ws + OFF_X1F; }
  else if (bx < 64) { W = Wc;   bias = bc;   ldw = 768; woff = 0;   c0 = (bx - 32) * 32; mode = 1; out = ws + OFF_XPRE; }
  else              { W = Ws_w; bias = Ws_b; ldw = 768; woff = 512; c0 = (bx - 64) * 32; mode = 2; out = ws + OFF_XB3; }

  for (int i = 0; i < 16; ++i)
    As[i * 258 + tid] = x[(t * 16 + i) * 256 + tid];
  for (int i = 0; i < 32; ++i)
    Wsh[tid * 34 + i] = W[(c0 + i) * ldw + woff + tid];
  __syncthreads();

  const int r = tid >> 4;
  const int c2 = (tid & 15) * 2;
  float acc0 = 0.f, acc1 = 0.f;
  for (int k = 0; k < 256; k += 2) {
    float2 a  = *(const float2*)&As[r * 258 + k];
    float2 w0 = *(const float2*)&Wsh[k * 34 + c2];
    float2 w1 = *(const float2*)&Wsh[(k + 1) * 34 + c2];
    acc0 = fmaf(a.x, w0.x, acc0); acc0 = fmaf(a.y, w1.x, acc0);
    acc1 = fmaf(a.x, w0.y, acc1); acc1 = fmaf(a.y, w1.y, acc1);
  }
  const int cg = c0 + c2;
  acc0 += bias[cg]; acc1 += bias[cg + 1];
  float2 res; res.x = acc0; res.y = acc1;
  if (mode == 0) {
    *(float2*)&out[((t * 64 + (cg >> 4)) * 16 + r) * 16 + (cg & 15)] = res;
  } else if (mode == 1) {
    *(float2*)&out[(t * 16 + r) * 1024 + cg] = res;
  } else {
    *(float2*)&out[(t * 16 + r) * 256 + cg] = res;
  }
}

// Shared LSTM: 2 WGs x 512 thr; W_hh resident in VGPRs, MFMA 16x16x32_f16.
// Exchange packs 2 f16 h-values per u64 record (tag in low32) — halves polls.
__global__ __launch_bounds__(512) void lstm_kernel(const float* __restrict__ X1F,
                                                   const float* __restrict__ W_hh,
                                                   float* __restrict__ hsB,
                                                   u64* __restrict__ hx){
  __shared__ unsigned hT[16 * 136];   // [b][k2], row stride 136 u32
  const int tid = threadIdx.x;
  const int wg = blockIdx.x;
  const int wave = tid >> 6, lane = tid & 63;
  const int b16 = lane & 15, quad = lane >> 4;
  const int jb = wg * 8 + wave;
  const int jpbase = (1 - wg) * 64;   // peer jp (k2) range base

  f16x8 wf[4][8];
  #pragma unroll
  for (int g = 0; g < 4; ++g) {
    #pragma unroll
    for (int kk = 0; kk < 8; ++kk) {
      int row = g * 256 + jb * 16 + b16;
      const float* wp = &W_hh[row * 256 + kk * 32 + quad * 8];
      f16x8 v;
      #pragma unroll
      for (int j = 0; j < 8; ++j) v[j] = (_Float16)wp[j];
      wf[g][kk] = v;
    }
  }
  for (int i = tid; i < 16 * 136; i += 512) hT[i] = 0u;
  float cst[4] = {0.f, 0.f, 0.f, 0.f};
  __syncthreads();

  for (int t = 0; t < T_LEN; ++t) {
    float4 xi[4];
    #pragma unroll
    for (int g = 0; g < 4; ++g)
      xi[g] = *(const float4*)&X1F[((t * 64 + g * 16 + jb) * 16 + b16) * 16 + quad * 4];

    if (t > 0) {
      const u64* src = &hx[((u64)((t - 1) & 1) * 128) * 16];
      #pragma unroll
      for (int cc = 0; cc < 2; ++cc) {
        int idx = tid * 2 + cc;         // 0..1023 peer pair-cells
        int jpp = idx >> 4, bbq = idx & 15;
        int jp = jpbase + jpp;
        u64 v;
        do { v = gld64(&src[jp * 16 + bbq]); } while ((unsigned)v != (unsigned)t);
        hT[bbq * 136 + jp] = (unsigned)(v >> 32);
      }
    }
    __syncthreads();

    f32x4 acc[4];
    #pragma unroll
    for (int g = 0; g < 4; ++g) {
      f32x4 a; a[0]=xi[g].x; a[1]=xi[g].y; a[2]=xi[g].z; a[3]=xi[g].w;
      acc[g] = a;
    }
    #pragma unroll
    for (int kk = 0; kk < 8; ++kk) {
      union { uint4 u; f16x8 h; } bv;
      bv.u = *(const uint4*)&hT[b16 * 136 + kk * 16 + quad * 4];
      #pragma unroll
      for (int g = 0; g < 4; ++g)
        acc[g] = __builtin_amdgcn_mfma_f32_16x16x32_f16(wf[g][kk], bv.h, acc[g], 0, 0, 0);
    }
    __syncthreads();

    float hv[4];
    #pragma unroll
    for (int r = 0; r < 4; ++r) {
      float pi = acc[0][r], pf = acc[1][r], pg = acc[2][r], po = acc[3][r];
      float cn = fmaf(sigm(pf), cst[r], sigm(pi) * tanh_f(pg));
      hv[r] = sigm(po) * tanh_f(cn);
      cst[r] = cn;
    }
    int j0 = jb * 16 + quad * 4;
    int jp = j0 >> 1;
    unsigned p01 = packh2(hv[0], hv[1]);
    unsigned p23 = packh2(hv[2], hv[3]);
    u64* dst = &hx[((u64)(t & 1) * 128) * 16];
    gst64(&dst[(jp)     * 16 + b16], ((u64)p01 << 32) | (unsigned)(t + 1));
    gst64(&dst[(jp + 1) * 16 + b16], ((u64)p23 << 32) | (unsigned)(t + 1));
    *(float4*)&hsB[(b16 * 192 + t) * 256 + j0] = make_float4(hv[0], hv[1], hv[2], hv[3]);
    hT[b16 * 136 + jp]     = p01;
    hT[b16 * 136 + jp + 1] = p23;
  }
}

// Task loop: 128 WGs x 1024 thr; bb = bid&15, s = bid>>4 owns c in [32s,32s+32).
// Producer-side hterm partials (ride the h exchange), hgate GEMV in p-RTT shadow,
// G-trick R elimination. 2 exchanges/step, 4 barriers/step.
__global__ __launch_bounds__(1024) void task_kernel(
    const float* __restrict__ xb3, const float* __restrict__ xpre,
    const float* __restrict__ hsB, const float* __restrict__ Us_w,
    const float* __restrict__ Us_b, const float* __restrict__ Wc,
    const float* __restrict__ Ws_w,
    u64* __restrict__ Pbuf, u64* __restrict__ Hbuf, u64* __restrict__ HPbuf,
    float* __restrict__ out){
  extern __shared__ char smem[];
  // prologue views
  unsigned* hsL  = (unsigned*)smem;               // [192][129] u32
  unsigned* Ws1L = (unsigned*)(smem + 99072);     // [32][129]
  float*    baseS= (float*)(smem + 115584);       // [192][33]
  // main views
  unsigned* WcH  = (unsigned*)smem;               // 16384 u32: Wc h-part
  unsigned* Ws2P = (unsigned*)(smem + 65536);     // [256 c][17] u32: Ws2 own-K slice
  float* prel    = (float*)(smem + 82944);        // [128][13]
  float* eel     = (float*)(smem + 89600);        // 192
  unsigned* h2l  = (unsigned*)(smem + 90368);     // 128 (full h pairs)
  unsigned* h2own= (unsigned*)(smem + 90880);     // 16 (own h slice pairs)
  float* hterml  = (float*)(smem + 90944);        // 32
  float* usl     = (float*)(smem + 91072);        // 32
  float* msc     = (float*)(smem + 91200);        // 1
  unsigned* G2   = (unsigned*)(smem + 99072);     // [128][97] u32

  const int tid = threadIdx.x;
  const int bb = blockIdx.x & 15;
  const int s  = blockIdx.x >> 4;

  // ---- P1: stage hs (f16) + Ws1 slice ----
  for (int idx = tid; idx < 24576; idx += 1024) {
    int tp = idx >> 7, k2 = idx & 127;
    const float* hp = &hsB[(bb * 192 + tp) * 256 + 2 * k2];
    hsL[tp * 129 + k2] = packh2(hp[0], hp[1]);
  }
  for (int idx = tid; idx < 4096; idx += 1024) {
    int c = idx >> 7, k2 = idx & 127;
    const float* wp = &Ws_w[(32 * s + c) * 768 + 2 * k2];
    Ws1L[c * 129 + k2] = packh2(wp[0], wp[1]);
  }
  __syncthreads();
  // ---- P2: base_s = xb3 + hs @ Ws1^T for [192 tp][own 32 c] ----
  {
    int c = tid & 31, g = tid >> 5;
    float a6[6];
    #pragma unroll
    for (int j = 0; j < 6; ++j)
      a6[j] = xb3[((g * 6 + j) * 16 + bb) * 256 + 32 * s + c];
    for (int k2 = 0; k2 < 128; ++k2) {
      unsigned wv = Ws1L[c * 129 + k2];
      #pragma unroll
      for (int j = 0; j < 6; ++j)
        a6[j] = fdot2(wv, hsL[(g * 6 + j) * 129 + k2], a6[j]);
    }
    #pragma unroll
    for (int j = 0; j < 6; ++j)
      baseS[(g * 6 + j) * 33 + c] = a6[j];
  }
  __syncthreads();
  // ---- P3a: persistent base registers (f16 pairs) ----
  unsigned bs4[4] = {0u, 0u, 0u, 0u};
  if (tid < 768) {
    int tp = tid >> 2, q = tid & 3;
    #pragma unroll
    for (int j2 = 0; j2 < 4; ++j2)
      bs4[j2] = packh2(baseS[tp * 33 + q * 8 + 2 * j2],
                       baseS[tp * 33 + q * 8 + 2 * j2 + 1]);
  }
  __syncthreads();
  // ---- P3b: G2[l][j] = f16 pairs over t of (Wc_R[l,:] @ hs[t,:]) ----
  {
    int l = tid & 127, tg = tid >> 7;
    int row = (l >> 5) * 256 + 32 * s + (l & 31);
    const float* wr = &Wc[row * 768 + 256];
    float acc[24];
    #pragma unroll
    for (int i = 0; i < 24; ++i) acc[i] = 0.f;
    for (int kc = 0; kc < 128; kc += 16) {
      unsigned wv[16];
      #pragma unroll
      for (int i = 0; i < 16; ++i) {
        float2 wp2 = *(const float2*)&wr[2 * (kc + i)];
        wv[i] = packh2(wp2.x, wp2.y);
      }
      #pragma unroll
      for (int tt = 0; tt < 24; ++tt) {
        const unsigned* hp = &hsL[(tg * 24 + tt) * 129 + kc];
        float a = acc[tt];
        #pragma unroll
        for (int i = 0; i < 16; ++i) a = fdot2(wv[i], hp[i], a);
        acc[tt] = a;
      }
    }
    #pragma unroll
    for (int i = 0; i < 12; ++i)
      G2[l * 97 + tg * 12 + i] = packh2(acc[2 * i], acc[2 * i + 1]);
  }
  __syncthreads();
  // ---- P4: main weight fills (overwrite hsL region) ----
  for (int idx = tid; idx < 16384; idx += 1024) {
    int j = idx & 3, l = (idx >> 2) & 127, k2q = idx >> 9;
    int k2 = k2q * 4 + j;
    int row = (l >> 5) * 256 + 32 * s + (l & 31);
    const float* wp = &Wc[row * 768 + 512 + 2 * k2];   // h-part cols
    WcH[idx] = packh2(wp[0], wp[1]);
  }
  for (int idx = tid; idx < 4096; idx += 1024) {
    int c = idx >> 4, j = idx & 15;                    // Ws2[:, own h K-slice]
    const float* wp = &Ws_w[c * 768 + 256 + 2 * (16 * s + j)];
    Ws2P[c * 17 + j] = packh2(wp[0], wp[1]);
  }
  if (tid < 32) usl[tid] = Us_w[32 * s + tid];
  const float usb = Us_b[0];
  __syncthreads();

  u64* Pb  = Pbuf + (bb * 8) * 192;
  u64* Hb  = Hbuf + bb * 256;
  u64* HPb = HPbuf + (bb * 8) * 256;       // [8 sp][256 c]
  const uint4* wp4 = (const uint4*)WcH;
  const uint4* av4 = (const uint4*)h2l;
  float creg = 0.f;       // c-state (tid<32)

  for (int t = 0; t < T_LEN; ++t) {
    const unsigned seq = (unsigned)(t + 1);
    float xp0 = 0.f, xp1 = 0.f, xp2 = 0.f, xp3 = 0.f;
    if (tid < 32) {
      const float* xq = &xpre[(t * 16 + bb) * 1024 + 32 * s + tid];
      xp0 = xq[0]; xp1 = xq[256]; xp2 = xq[512]; xp3 = xq[768];
    }
    // S1: poll h (full) + hterm partials (own 32 c), one RTT
    if (t > 0) {
      if (tid < 256) {
        int c = tid >> 3, sp = tid & 7;       // all 8 sp for c within one wave
        u64 v;
        do { v = gld64(&HPb[sp * 256 + 32 * s + c]); } while ((unsigned)v != (unsigned)t);
        float a = __uint_as_float((unsigned)(v >> 32));
        a += __shfl_xor(a, 1); a += __shfl_xor(a, 2); a += __shfl_xor(a, 4);
        if (sp == 0) hterml[c] = a;
      } else if (tid < 512) {
        int col = tid - 256;
        u64 v;
        do { v = gld64(&Hb[col]); } while ((unsigned)v != (unsigned)t);
        float hvv = __uint_as_float((unsigned)(v >> 32));
        float hp_ = __shfl_xor(hvv, 1);
        if ((col & 1) == 0) h2l[col >> 1] = packh2(hvv, hp_);
      }
    } else {
      if (tid < 32) hterml[tid] = 0.f;
      if (tid < 128) h2l[tid] = 0u;
    }
    __syncthreads();                 // B1
    // S5: score partials over own 32 c for all 192 tp; publish p_s
    if (tid < 768) {
      int tp = tid >> 2, q = tid & 3;
      float p = 0.f;
      #pragma unroll
      for (int m = 0; m < 4; ++m) {
        float2 bv = unp2(bs4[m]);
        int c0 = q * 8 + 2 * m;
        p += usl[c0]     * tanh_f(bv.x + hterml[c0]);
        p += usl[c0 + 1] * tanh_f(bv.y + hterml[c0 + 1]);
      }
      p += __shfl_xor(p, 1);
      p += __shfl_xor(p, 2);
      if ((tid & 3) == 0)
        gst64(&Pb[s * 192 + tp], ((u64)__float_as_uint(p) << 32) | seq);
    }
    // hgate GEMV (p-RTT shadow): pre_h[l] partials, 8-way K-split
    {
      int l = tid & 127, kq = tid >> 7;
      float a = 0.f;
      #pragma unroll
      for (int i = 0; i < 4; ++i) {
        uint4 w4 = wp4[(kq * 4 + i) * 128 + l];
        uint4 a4 = av4[kq * 4 + i];
        a = fdot2(w4.x, a4.x, a); a = fdot2(w4.y, a4.y, a);
        a = fdot2(w4.z, a4.z, a); a = fdot2(w4.w, a4.w, a);
      }
      prel[l * 13 + kq] = a;
    }
    // S6: p poll + exp (bounded scores, no max-sub)
    if (tid < 192) {
      u64 v[8];
      for (;;) {
        bool ok = true;
        #pragma unroll
        for (int sp = 0; sp < 8; ++sp) {
          v[sp] = gld64(&Pb[sp * 192 + tid]);
          ok &= ((unsigned)v[sp] == seq);
        }
        if (ok) break;
      }
      float sum = 0.f;
      #pragma unroll
      for (int sp = 0; sp < 8; ++sp) sum += __uint_as_float((unsigned)(v[sp] >> 32));
      eel[tid] = __expf(sum + usb);
    }
    __syncthreads();                 // B5
    // msc reduce (wave0) + G-part (tid>=512)
    if (tid < 64) {
      float aa = eel[tid] + eel[tid + 64] + eel[tid + 128];
      #pragma unroll
      for (int off = 32; off >= 1; off >>= 1) aa += __shfl_xor(aa, off);
      if (tid == 0) msc[0] = 1.f / aa;
    }
    if (tid >= 512) {
      int l = (tid - 512) & 127, tq = (tid - 512) >> 7;
      const unsigned* gp = &G2[l * 97 + tq * 24];
      const float2* ep = (const float2*)&eel[tq * 48];
      float a = 0.f;
      #pragma unroll
      for (int i = 0; i < 24; ++i) {
        float2 g = unp2(gp[i]);
        float2 e = ep[i];
        a = fmaf(g.x, e.x, a); a = fmaf(g.y, e.y, a);
      }
      prel[l * 13 + 8 + tq] = a;
    }
    __syncthreads();                 // B9
    // epilogue: gates for own 32 h-cols; publish h early
    if (tid < 32) {
      float m = msc[0];
      float pr[4];
      #pragma unroll
      for (int g = 0; g < 4; ++g) {
        const float* pp = &prel[(g * 32 + tid) * 13];
        float hsum = pp[0] + pp[1] + pp[2] + pp[3] + pp[4] + pp[5] + pp[6] + pp[7];
        float gsum = pp[8] + pp[9] + pp[10] + pp[11];
        pr[g] = hsum + m * gsum;
      }
      pr[0] += xp0; pr[1] += xp1; pr[2] += xp2; pr[3] += xp3;
      float cn = fmaf(sigm(pr[1]), creg, sigm(pr[0]) * tanh_f(pr[2]));
      float hh = sigm(pr[3]) * tanh_f(cn);
      creg = cn;
      gst64(&Hb[32 * s + tid], ((u64)__float_as_uint(hh) << 32) | seq);
      out[(bb * 192 + t) * 256 + 32 * s + tid] = hh;
      float hp_ = __shfl_xor(hh, 1);
      if ((tid & 1) == 0) h2own[tid >> 1] = packh2(hh, hp_);
    }
    __syncthreads();                 // B10
    // producer-side hterm partials: hpart[c] = Ws2[c, own K] @ h_own; publish
    if (tid < 256) {
      float a = 0.f;
      const unsigned* wp = &Ws2P[tid * 17];
      #pragma unroll
      for (int j = 0; j < 16; ++j) a = fdot2(wp[j], h2own[j], a);
      gst64(&HPb[s * 256 + tid], ((u64)__float_as_uint(a) << 32) | seq);
    }
  }
}

extern "C" void kernel_launch(void* const* d_in, const int* in_sizes, int n_in,
                              void* d_out, int out_size, void* d_ws, size_t ws_size,
                              hipStream_t stream) {
  (void)in_sizes; (void)n_in; (void)out_size; (void)ws_size;
  const float* x    = (const float*)d_in[0];
  const float* W_ih = (const float*)d_in[1];
  const float* W_hh = (const float*)d_in[2];
  const float* b_l  = (const float*)d_in[3];
  const float* Ws_w = (const float*)d_in[4];
  const float* Ws_b = (const float*)d_in[5];
  const float* Us_w = (const float*)d_in[6];
  const float* Us_b = (const float*)d_in[7];
  const float* Wc   = (const float*)d_in[8];
  const float* bc   = (const float*)d_in[9];
  float* out = (float*)d_out;
  float* ws = (float*)d_ws;

  hipFuncSetAttribute((const void*)task_kernel,
                      hipFuncAttributeMaxDynamicSharedMemorySize, 160 * 1024);

  // zero exchange region (P, H, HX, HP — seq tags restart at 1 each launch)
  initk<<<64, 256, 0, stream>>>(ws + OFF_P, EXCH_WORDS);

  // fused x-projections: X1F, xpre, xb3
  proj3<<<dim3(72, 192), 256, 0, stream>>>(x, W_ih, b_l, Wc, bc, Ws_w, Ws_b, ws);

  // shared LSTM: 2 persistent WGs, W_hh in VGPRs via MFMA
  lstm_kernel<<<2, 512, 0, stream>>>(ws + OFF_X1F, W_hh, ws + OFF_HSB,
                                     (u64*)(ws + OFF_HX));

  // task loop
  task_kernel<<<128, 1024, SMEM_TASK, stream>>>(
      ws + OFF_XB3, ws + OFF_XPRE, ws + OFF_HSB, Us_w, Us_b, Wc, Ws_w,
      (u64*)(ws + OFF_P), (u64*)(ws + OFF_H), (u64*)(ws + OFF_HP), out);
}